// Round 13
// baseline (635.146 us; speedup 1.0000x reference)
//
#include <hip/hip_runtime.h>

typedef unsigned short u16;
typedef unsigned int u32;
typedef __attribute__((ext_vector_type(4))) float f32x4;
typedef __attribute__((ext_vector_type(8))) short s16x8;

#define GM 262144   // B*N rows
#define GB 64
#define GN 4096
#define GS 8
#define NPART 16    // PX-partial blocks per batch

__device__ __forceinline__ float bf2f(u16 u) {
  union { unsigned int i; float f; } c; c.i = ((unsigned int)u) << 16; return c.f;
}
__device__ __forceinline__ u16 f2bf(float f) {
  union { float f; unsigned int i; } c; c.f = f;
  unsigned int x = c.i;
  unsigned int r = x + 0x7FFFu + ((x >> 16) & 1u);
  return (u16)(r >> 16);
}
__device__ __forceinline__ float dot4(f32x4 a, f32x4 b) {
  return a.x*b.x + a.y*b.y + a.z*b.z + a.w*b.w;
}

// ---------------- slots init ----------------
__global__ void init_slots_kernel(const float* __restrict__ noise, const float* __restrict__ smu,
                                  const float* __restrict__ sls, float* __restrict__ slots)
{
  int i = blockIdx.x * 256 + threadIdx.x;
  int d = i & 255;
  slots[i] = smu[d] + expf(sls[d]) * noise[i];
}

// ---------------- weight prep: wkv(Wv part used), Wcat, W1b, W2b (bf16) ----------------
__global__ void wprep_kernel(const float* __restrict__ Wk, const float* __restrict__ Wv,
                             const float* __restrict__ Wih, const float* __restrict__ Whh,
                             const float* __restrict__ W1, const float* __restrict__ W2,
                             u16* __restrict__ wkv, u16* __restrict__ Wcat,
                             u16* __restrict__ W1b, u16* __restrict__ W2b)
{
  int i = blockIdx.x * 256 + threadIdx.x;       // 917504 total
  if (i < 131072) {
    wkv[i] = f2bf(i < 65536 ? Wk[i] : Wv[i - 65536]);
  } else if (i < 655360) {
    int j2 = i - 131072;
    int r = j2 >> 9, k = j2 & 511;
    float v;
    if (r < 512)      v = (k < 256) ? Wih[r * 256 + k] : Whh[r * 256 + (k - 256)];
    else if (r < 768) v = (k < 256) ? Wih[r * 256 + k] : 0.f;
    else              v = (k < 256) ? 0.f : Whh[(r - 256) * 256 + (k - 256)];
    Wcat[j2] = f2bf(v);
  } else if (i < 786432) {
    W1b[i - 655360] = f2bf(W1[i - 655360]);
  } else {
    W2b[i - 786432] = f2bf(W2[i - 786432]);
  }
}

// ---------------- WqkT = SCALE * Wk^T @ Wq ----------------
__global__ __launch_bounds__(256) void wqk_kernel(
    const float* __restrict__ Wk, const float* __restrict__ Wq,
    float* __restrict__ WqkT, u16* __restrict__ WqkTb)
{
  __shared__ float wkc[256];
  int c = blockIdx.x, t = threadIdx.x;
  wkc[t] = Wk[t * 256 + c];
  __syncthreads();
  float a0 = 0.f, a1 = 0.f, a2 = 0.f, a3 = 0.f;
  #pragma unroll 4
  for (int d = 0; d < 256; d += 4) {
    a0 += wkc[d]     * Wq[(d)     * 256 + t];
    a1 += wkc[d + 1] * Wq[(d + 1) * 256 + t];
    a2 += wkc[d + 2] * Wq[(d + 2) * 256 + t];
    a3 += wkc[d + 3] * Wq[(d + 3) * 256 + t];
  }
  float acc = (a0 + a1 + a2 + a3) * 0.0625f;
  WqkT[c * 256 + t] = acc;
  WqkTb[c * 256 + t] = f2bf(acc);
}

// ---------------- LN(inputs) -> bf16 xbuf (single layout) ----------------
__global__ __launch_bounds__(256) void ln_bf16_kernel(
    const float* __restrict__ x, const float* __restrict__ g, const float* __restrict__ be,
    u16* __restrict__ xbuf)
{
  int row = blockIdx.x * 4 + (threadIdx.x >> 6);
  int lane = threadIdx.x & 63;
  f32x4 v = *(const f32x4*)&x[(size_t)row * 256 + lane * 4];
  float s = v.x + v.y + v.z + v.w;
  float sq = v.x*v.x + v.y*v.y + v.z*v.z + v.w*v.w;
  #pragma unroll
  for (int m = 1; m < 64; m <<= 1) { s += __shfl_xor(s, m, 64); sq += __shfl_xor(sq, m, 64); }
  float mu = s * (1.f / 256.f);
  float var = sq * (1.f / 256.f) - mu * mu;
  float rstd = rsqrtf(var + 1e-3f);
  f32x4 gv = *(const f32x4*)&g[lane * 4];
  f32x4 bv = *(const f32x4*)&be[lane * 4];
  uint2 pk;
  pk.x = (u32)f2bf((v.x - mu) * rstd * gv.x + bv.x)
       | ((u32)f2bf((v.y - mu) * rstd * gv.y + bv.y) << 16);
  pk.y = (u32)f2bf((v.z - mu) * rstd * gv.z + bv.z)
       | ((u32)f2bf((v.w - mu) * rstd * gv.w + bv.w) << 16);
  *(uint2*)&xbuf[(size_t)row * 256 + lane * 4] = pk;
}

// ---------------- slot LN + q->input-space projection (iter 0 only) ----------------
__global__ __launch_bounds__(256) void qproj_kernel(const float* __restrict__ slots,
    const float* __restrict__ WqkT,
    const float* __restrict__ g, const float* __restrict__ be, float* __restrict__ gqk)
{
  __shared__ __align__(16) float sl[8][256];
  int b = blockIdx.x, t = threadIdx.x;
  int lane = t & 63, w = t >> 6;
  #pragma unroll
  for (int s2 = 0; s2 < 2; ++s2) {
    int s = w * 2 + s2;
    f32x4 v = *(const f32x4*)&slots[(size_t)(b * 8 + s) * 256 + lane * 4];
    float s1 = v.x + v.y + v.z + v.w;
    float q1 = v.x*v.x + v.y*v.y + v.z*v.z + v.w*v.w;
    #pragma unroll
    for (int m = 1; m < 64; m <<= 1) { s1 += __shfl_xor(s1, m, 64); q1 += __shfl_xor(q1, m, 64); }
    float mu = s1 * (1.f / 256.f);
    float var = q1 * (1.f / 256.f) - mu * mu;
    float rstd = rsqrtf(var + 1e-3f);
    f32x4 gv = *(const f32x4*)&g[lane * 4];
    f32x4 bv = *(const f32x4*)&be[lane * 4];
    f32x4 o;
    o.x = (v.x - mu) * rstd * gv.x + bv.x;
    o.y = (v.y - mu) * rstd * gv.y + bv.y;
    o.z = (v.z - mu) * rstd * gv.z + bv.z;
    o.w = (v.w - mu) * rstd * gv.w + bv.w;
    *(f32x4*)&sl[s][lane * 4] = o;
  }
  __syncthreads();
  float a[8];
  #pragma unroll
  for (int s = 0; s < 8; ++s) a[s] = 0.f;
  const f32x4* wr = (const f32x4*)&WqkT[(size_t)t * 256];
  for (int k = 0; k < 64; ++k) {
    f32x4 w4 = wr[k];
    #pragma unroll
    for (int s = 0; s < 8; ++s) a[s] += dot4(w4, *(const f32x4*)&sl[s][k * 4]);
  }
  #pragma unroll
  for (int s = 0; s < 8; ++s) gqk[(size_t)(b * 8 + s) * 256 + t] = a[s];
}

// ---------------- single-layout attention, register-prefetch pipeline (T14) ----------------
// grid (16, 64), block 256 = 4 waves. Single 32 KB X buffer (4 blocks/CU by LDS).
// Per tile: [issue next-tile global loads into regs] -> dots -> softmax/P -> B ->
// PV -> B -> vmcnt(0) (landed under compute) -> ds_write X -> B. No exposed stall.
__global__ __launch_bounds__(256) void attn_kernel(
    const u16* __restrict__ xb, const float* __restrict__ gqk,
    float* __restrict__ gUp, float* __restrict__ gdp)
{
  __shared__ __align__(16) u16 X[64 * 256];     // swizzled tile, 32 KB
  __shared__ __align__(16) u16 P[16 * 72];      // P[s][n] bf16 (rows 8..15 zero)
  __shared__ float denL[4][8];
  const int b = blockIdx.y, chunk = blockIdx.x;
  const int t = threadIdx.x;
  const int lane = t & 63, w = t >> 6;
  const int fr = lane & 15, fq = lane >> 4;
  const bool valid = fr < 8;

  // zero P rows 8..15 once (never written again)
  for (int i = t; i < 288; i += 256) ((u32*)P)[288 + i] = 0;

  // per-thread swizzled stage offsets (u16 units, same for every tile)
  int off[8];
  #pragma unroll
  for (int p = 0; p < 8; ++p) {
    int q = p * 256 + t;
    int n = q >> 5, cl = q & 31;
    int fn = ((n >> 1) & 4) | ((n >> 3) & 2);
    off[p] = n * 256 + ((cl ^ fn) * 8);
  }

  const u16* xbase = xb + (size_t)b * 4096 * 256 + (size_t)chunk * 4 * 64 * 256;

  // --- prologue: prefetch tile 0 into regs ---
  uint4 pf[8];
  #pragma unroll
  for (int p = 0; p < 8; ++p) pf[p] = *(const uint4*)(xbase + off[p]);

  // --- q fragments (overlaps prefetch latency): slot = fr ---
  s16x8 qf[8];
  if (valid) {
    const float* qr = gqk + (size_t)b * 2048 + fr * 256;
    #pragma unroll
    for (int ks = 0; ks < 8; ++ks) {
      f32x4 a = *(const f32x4*)&qr[ks * 32 + fq * 8];
      f32x4 c = *(const f32x4*)&qr[ks * 32 + fq * 8 + 4];
      s16x8 q8;
      q8[0] = (short)f2bf(a.x); q8[1] = (short)f2bf(a.y);
      q8[2] = (short)f2bf(a.z); q8[3] = (short)f2bf(a.w);
      q8[4] = (short)f2bf(c.x); q8[5] = (short)f2bf(c.y);
      q8[6] = (short)f2bf(c.z); q8[7] = (short)f2bf(c.w);
      qf[ks] = q8;
    }
  } else {
    #pragma unroll
    for (int ks = 0; ks < 8; ++ks) { s16x8 z = {0,0,0,0,0,0,0,0}; qf[ks] = z; }
  }

  // write tile 0
  asm volatile("s_waitcnt vmcnt(0)" ::: "memory");
  __builtin_amdgcn_sched_barrier(0);
  #pragma unroll
  for (int p = 0; p < 8; ++p) *(uint4*)&X[(p * 256 + t) * 8] = pf[p];
  asm volatile("s_waitcnt lgkmcnt(0)" ::: "memory");
  __builtin_amdgcn_sched_barrier(0);
  __builtin_amdgcn_s_barrier();                  // X(0) ready
  __builtin_amdgcn_sched_barrier(0);

  // swizzle constants: f(n) = (n.bit3 << 2) | (n.bit4 << 1)
  const int fnA = ((fr >> 1) & 4) | ((w & 1) << 1);       // dots rows: n = w*16 + fr
  const int fnB = ((fq & 1) << 2) | ((fq >> 1) << 1);     // PV cols

  float denom_loc = 0.f;
  f32x4 uacc[4];
  #pragma unroll
  for (int ct = 0; ct < 4; ++ct) { f32x4 z = {0.f,0.f,0.f,0.f}; uacc[ct] = z; }

  for (int ti = 0; ti < 4; ++ti) {
    // issue next tile's loads FIRST (they land under this tile's compute)
    if (ti < 3) {
      const u16* src = xbase + (size_t)(ti + 1) * 16384;
      #pragma unroll
      for (int p = 0; p < 8; ++p) pf[p] = *(const uint4*)(src + off[p]);
    }
    __builtin_amdgcn_sched_barrier(0);           // loads issued before compute

    // --- dots: wave w -> rows n = w*16 + fr ; D[n][s] ---
    f32x4 dacc = {0.f, 0.f, 0.f, 0.f};
    {
      const u16* xrow = &X[(w * 16 + fr) * 256];
      #pragma unroll
      for (int ks = 0; ks < 8; ++ks) {
        s16x8 a = *(const s16x8*)&xrow[(((ks * 4 + fq) ^ fnA) * 8)];
        dacc = __builtin_amdgcn_mfma_f32_16x16x32_bf16(a, qf[ks], dacc, 0, 0, 0);
      }
    }
    // --- softmax over slots (fr bits 0..2); rows n = w*16 + fq*4 + r ---
    float pw[4];
    #pragma unroll
    for (int r = 0; r < 4; ++r) {
      float d = dacc[r];
      float m = d;
      #pragma unroll
      for (int msk = 1; msk < 8; msk <<= 1) m = fmaxf(m, __shfl_xor(m, msk, 64));
      float e = expf(d - m);
      float sm = e;
      #pragma unroll
      for (int msk = 1; msk < 8; msk <<= 1) sm += __shfl_xor(sm, msk, 64);
      pw[r] = valid ? (e / sm + 1e-8f) : 0.f;
    }
    denom_loc += pw[0] + pw[1] + pw[2] + pw[3];
    if (valid) {
      u32* p32 = (u32*)P;
      int pi = fr * 36 + w * 8 + fq * 2;
      p32[pi]     = (u32)f2bf(pw[0]) | ((u32)f2bf(pw[1]) << 16);
      p32[pi + 1] = (u32)f2bf(pw[2]) | ((u32)f2bf(pw[3]) << 16);
    }
    asm volatile("s_waitcnt lgkmcnt(0)" ::: "memory");
    __builtin_amdgcn_sched_barrier(0);
    __builtin_amdgcn_s_barrier();                // B: P complete (all waves)
    __builtin_amdgcn_sched_barrier(0);

    // --- PV: U[s][c], wave w -> c in [w*64, w*64+64); X^T via LDS column reads ---
    #pragma unroll
    for (int ch = 0; ch < 2; ++ch) {
      s16x8 pa = *(const s16x8*)&P[fr * 72 + ch * 32 + fq * 8];
      #pragma unroll
      for (int ct = 0; ct < 4; ++ct) {
        int c = w * 64 + ct * 16 + fr;
        const u16* xcol = &X[(ch * 32 + fq * 8) * 256 + (((c >> 3) ^ fnB) * 8) + (c & 7)];
        union { s16x8 v; u32 u[4]; } vb;
        #pragma unroll
        for (int jj = 0; jj < 4; ++jj) {
          u16 e0 = xcol[(jj * 2) * 256];
          u16 e1 = xcol[(jj * 2 + 1) * 256];
          vb.u[jj] = (u32)e0 | ((u32)e1 << 16);
        }
        uacc[ct] = __builtin_amdgcn_mfma_f32_16x16x32_bf16(pa, vb.v, uacc[ct], 0, 0, 0);
      }
    }

    if (ti < 3) {
      __builtin_amdgcn_s_barrier();              // B: all X/P reads done -> safe to overwrite
      __builtin_amdgcn_sched_barrier(0);
      asm volatile("s_waitcnt vmcnt(0)" ::: "memory");   // prefetched regs landed (hidden)
      __builtin_amdgcn_sched_barrier(0);
      #pragma unroll
      for (int p = 0; p < 8; ++p) *(uint4*)&X[(p * 256 + t) * 8] = pf[p];
      asm volatile("s_waitcnt lgkmcnt(0)" ::: "memory");
      __builtin_amdgcn_sched_barrier(0);
      __builtin_amdgcn_s_barrier();              // B: X(next) ready
      __builtin_amdgcn_sched_barrier(0);
    }
  }

  // --- epilogue: wave-owned U columns -> f32 partial; denom block-reduce ---
  float dl = denom_loc;
  dl += __shfl_xor(dl, 16, 64);
  dl += __shfl_xor(dl, 32, 64);
  if (lane < 8) denL[w][lane] = dl;
  if (fq < 2) {
    size_t obase = (size_t)(b * NPART + chunk) * 2048;
    #pragma unroll
    for (int ct = 0; ct < 4; ++ct)
      #pragma unroll
      for (int r = 0; r < 4; ++r)
        gUp[obase + (size_t)(fq * 4 + r) * 256 + w * 64 + ct * 16 + fr] = uacc[ct][r];
  }
  __syncthreads();
  if (t < 8) gdp[(b * NPART + chunk) * 8 + t] = denL[0][t] + denL[1][t] + denL[2][t] + denL[3][t];
}

// ---------------- update: Wv-proj + GRU + LN + MLP (+ fused next-iter qproj) ----------------
__global__ __launch_bounds__(256) void update_kernel(
    const float* __restrict__ gUp, const float* __restrict__ gdp,
    float* __restrict__ slots,
    const u16* __restrict__ WvB,
    const u16* __restrict__ Wcat, const float* __restrict__ b_ih, const float* __restrict__ b_hh,
    const u16* __restrict__ W1b, const float* __restrict__ b1,
    const u16* __restrict__ W2b, const float* __restrict__ b2,
    const float* __restrict__ lng, const float* __restrict__ lnb,
    const u16* __restrict__ WqkTb, const float* __restrict__ lnsg, const float* __restrict__ lnsb,
    float* __restrict__ gqk, float* __restrict__ out, int last)
{
  __shared__ __align__(16) u16 bufA[16 * 520];
  __shared__ __align__(16) u16 bufP[16 * 264];
  __shared__ __align__(16) u16 bufU[16 * 264];
  __shared__ float g[1024 * 10];
  __shared__ float nl[8 * 256];
  __shared__ float sp[8 * 256];
  __shared__ float scr[16];
  const int b = blockIdx.x;
  const int t = threadIdx.x;
  const int lane = t & 63, w = t >> 6;
  const int fr = lane & 15, fq = lane >> 4;

  // ---- phase 0 ----
  #pragma unroll
  for (int s = 0; s < 8; ++s) {
    float den = 0.f, ua = 0.f;
    #pragma unroll 4
    for (int c = 0; c < NPART; ++c) {
      den += gdp[(b * NPART + c) * 8 + s];
      ua  += gUp[(size_t)(b * NPART + c) * 2048 + s * 256 + t];
    }
    bufU[s * 264 + t] = f2bf(ua / den);
    float spv = slots[(b * 8 + s) * 256 + t];
    bufA[s * 520 + 256 + t] = f2bf(spv);
    sp[s * 256 + t] = spv;
  }
  for (int i = t; i < 8 * 520; i += 256) bufA[8 * 520 + i] = 0;
  for (int i = t; i < 8 * 264; i += 256) { bufP[8 * 264 + i] = 0; bufU[8 * 264 + i] = 0; }
  __syncthreads();

  // ---- phase 0b: updates = PXn @ Wv^T -> bufA u-half ----
  {
    s16x8 pa[8];
    #pragma unroll
    for (int ks = 0; ks < 8; ++ks)
      pa[ks] = *(const s16x8*)&bufU[fr * 264 + ks * 32 + fq * 8];
    for (int nf = 0; nf < 4; ++nf) {
      int n0 = w * 64 + nf * 16;
      f32x4 acc = {0.f, 0.f, 0.f, 0.f};
      #pragma unroll
      for (int ks = 0; ks < 8; ++ks) {
        s16x8 bb = *(const s16x8*)&WvB[(size_t)(n0 + fr) * 256 + ks * 32 + fq * 8];
        acc = __builtin_amdgcn_mfma_f32_16x16x32_bf16(pa[ks], bb, acc, 0, 0, 0);
      }
      if (fq < 2) {
        int d = n0 + fr;
        #pragma unroll
        for (int r = 0; r < 4; ++r)
          bufA[(fq * 4 + r) * 520 + d] = f2bf(acc[r]);
      }
    }
  }
  __syncthreads();

  // ---- phase 1: gates GEMM M=16 N=1024 K=512 ----
  {
    s16x8 afr[16];
    #pragma unroll
    for (int ks = 0; ks < 16; ++ks)
      afr[ks] = *(const s16x8*)&bufA[fr * 520 + ks * 32 + fq * 8];
    for (int nf = 0; nf < 16; ++nf) {
      int n0 = w * 256 + nf * 16;
      f32x4 acc = {0.f, 0.f, 0.f, 0.f};
      #pragma unroll
      for (int ks = 0; ks < 16; ++ks) {
        s16x8 bb = *(const s16x8*)&Wcat[(size_t)(n0 + fr) * 512 + ks * 32 + fq * 8];
        acc = __builtin_amdgcn_mfma_f32_16x16x32_bf16(afr[ks], bb, acc, 0, 0, 0);
      }
      if (fq < 2) {
        int j = n0 + fr;
        #pragma unroll
        for (int r = 0; r < 4; ++r) g[j * 10 + fq * 4 + r] = acc[r];
      }
    }
  }
  __syncthreads();

  // ---- phase 2: GRU elementwise ----
  {
    float bi0 = b_ih[t],       bh0 = b_hh[t];
    float bi1 = b_ih[256 + t], bh1 = b_hh[256 + t];
    float bi2 = b_ih[512 + t], bh2 = b_hh[512 + t];
    #pragma unroll
    for (int s = 0; s < 8; ++s) {
      float rr = 1.f / (1.f + expf(-(g[t * 10 + s] + bi0 + bh0)));
      float z  = 1.f / (1.f + expf(-(g[(256 + t) * 10 + s] + bi1 + bh1)));
      float xn = g[(512 + t) * 10 + s] + bi2;
      float hn = g[(768 + t) * 10 + s] + bh2;
      float nn = tanhf(xn + rr * hn);
      nl[s * 256 + t] = (1.f - z) * nn + z * sp[s * 256 + t];
    }
  }
  __syncthreads();

  // ---- LN_ff ----
  {
    int ln_ = t & 63;
    #pragma unroll
    for (int j = 0; j < 2; ++j) {
      int sl = w * 2 + j;
      f32x4 v = *(const f32x4*)&nl[sl * 256 + ln_ * 4];
      float s1 = v.x + v.y + v.z + v.w;
      float s2 = v.x*v.x + v.y*v.y + v.z*v.z + v.w*v.w;
      #pragma unroll
      for (int m = 1; m < 64; m <<= 1) { s1 += __shfl_xor(s1, m, 64); s2 += __shfl_xor(s2, m, 64); }
      if (ln_ == 0) {
        float mu = s1 * (1.f / 256.f);
        float var = s2 * (1.f / 256.f) - mu * mu;
        scr[sl * 2] = mu;
        scr[sl * 2 + 1] = rsqrtf(var + 1e-3f);
      }
    }
  }
  __syncthreads();
  {
    float lg = lng[t], lb = lnb[t];
    #pragma unroll
    for (int s = 0; s < 8; ++s)
      bufP[s * 264 + t] = f2bf((nl[s * 256 + t] - scr[s * 2]) * scr[s * 2 + 1] * lg + lb);
  }
  __syncthreads();

  // ---- phase 3: MLP1 M=16 N=512 K=256, relu ----
  {
    s16x8 pa[8];
    #pragma unroll
    for (int ks = 0; ks < 8; ++ks)
      pa[ks] = *(const s16x8*)&bufP[fr * 264 + ks * 32 + fq * 8];
    for (int nf = 0; nf < 8; ++nf) {
      int n0 = w * 128 + nf * 16;
      f32x4 acc = {0.f, 0.f, 0.f, 0.f};
      #pragma unroll
      for (int ks = 0; ks < 8; ++ks) {
        s16x8 bb = *(const s16x8*)&W1b[(size_t)(n0 + fr) * 256 + ks * 32 + fq * 8];
        acc = __builtin_amdgcn_mfma_f32_16x16x32_bf16(pa[ks], bb, acc, 0, 0, 0);
      }
      if (fq < 2) {
        float bb1 = b1[n0 + fr];
        #pragma unroll
        for (int r = 0; r < 4; ++r)
          bufA[(fq * 4 + r) * 520 + n0 + fr] = f2bf(fmaxf(acc[r] + bb1, 0.f));
      }
    }
  }
  __syncthreads();

  // ---- phase 4: MLP2 M=16 N=256 K=512, +residual; new slots -> sp ----
  {
    s16x8 ha[16];
    #pragma unroll
    for (int ks = 0; ks < 16; ++ks)
      ha[ks] = *(const s16x8*)&bufA[fr * 520 + ks * 32 + fq * 8];
    for (int nf = 0; nf < 4; ++nf) {
      int n0 = w * 64 + nf * 16;
      f32x4 acc = {0.f, 0.f, 0.f, 0.f};
      #pragma unroll
      for (int ks = 0; ks < 16; ++ks) {
        s16x8 bb = *(const s16x8*)&W2b[(size_t)(n0 + fr) * 512 + ks * 32 + fq * 8];
        acc = __builtin_amdgcn_mfma_f32_16x16x32_bf16(ha[ks], bb, acc, 0, 0, 0);
      }
      if (fq < 2) {
        int d = n0 + fr;
        float bb2 = b2[d];
        #pragma unroll
        for (int r = 0; r < 4; ++r) {
          int sl = fq * 4 + r;
          float val = acc[r] + nl[sl * 256 + d] + bb2;
          slots[(b * 8 + sl) * 256 + d] = val;
          sp[sl * 256 + d] = val;
          if (last) out[(b * 8 + sl) * 256 + d] = val;
        }
      }
    }
  }
  if (last) return;
  __syncthreads();

  // ---- fused next-iter qproj: gqk = LN_s(new slots) @ WqkT (SCALE folded) ----
  {
    int ln_ = t & 63;
    #pragma unroll
    for (int j = 0; j < 2; ++j) {
      int sl = w * 2 + j;
      f32x4 v = *(const f32x4*)&sp[sl * 256 + ln_ * 4];
      float s1 = v.x + v.y + v.z + v.w;
      float s2 = v.x*v.x + v.y*v.y + v.z*v.z + v.w*v.w;
      #pragma unroll
      for (int m = 1; m < 64; m <<= 1) { s1 += __shfl_xor(s1, m, 64); s2 += __shfl_xor(s2, m, 64); }
      if (ln_ == 0) {
        float mu = s1 * (1.f / 256.f);
        float var = s2 * (1.f / 256.f) - mu * mu;
        scr[sl * 2] = mu;
        scr[sl * 2 + 1] = rsqrtf(var + 1e-3f);
      }
    }
  }
  __syncthreads();
  {
    float lg = lnsg[t], lb = lnsb[t];
    #pragma unroll
    for (int s = 0; s < 8; ++s)
      bufP[s * 264 + t] = f2bf((sp[s * 256 + t] - scr[s * 2]) * scr[s * 2 + 1] * lg + lb);
  }
  __syncthreads();
  {
    s16x8 pa[8];
    #pragma unroll
    for (int ks = 0; ks < 8; ++ks)
      pa[ks] = *(const s16x8*)&bufP[fr * 264 + ks * 32 + fq * 8];
    for (int nf = 0; nf < 4; ++nf) {
      int n0 = w * 64 + nf * 16;
      f32x4 acc = {0.f, 0.f, 0.f, 0.f};
      #pragma unroll
      for (int ks = 0; ks < 8; ++ks) {
        s16x8 bb = *(const s16x8*)&WqkTb[(size_t)(n0 + fr) * 256 + ks * 32 + fq * 8];
        acc = __builtin_amdgcn_mfma_f32_16x16x32_bf16(pa[ks], bb, acc, 0, 0, 0);
      }
      if (fq < 2) {
        int e = n0 + fr;
        #pragma unroll
        for (int r = 0; r < 4; ++r)
          gqk[(size_t)(b * 8 + fq * 4 + r) * 256 + e] = acc[r];
      }
    }
  }
}

extern "C" void kernel_launch(void* const* d_in, const int* in_sizes, int n_in,
                              void* d_out, int out_size, void* d_ws, size_t ws_size,
                              hipStream_t stream) {
  const float* inputs   = (const float*)d_in[0];
  const float* noise    = (const float*)d_in[1];
  const float* slots_mu = (const float*)d_in[2];
  const float* slots_ls = (const float*)d_in[3];
  const float* Wq   = (const float*)d_in[4];
  const float* Wk   = (const float*)d_in[5];
  const float* Wv   = (const float*)d_in[6];
  const float* W_ih = (const float*)d_in[7];
  const float* W_hh = (const float*)d_in[8];
  const float* b_ih = (const float*)d_in[9];
  const float* b_hh = (const float*)d_in[10];
  const float* W1   = (const float*)d_in[11];
  const float* b1   = (const float*)d_in[12];
  const float* W2   = (const float*)d_in[13];
  const float* b2   = (const float*)d_in[14];
  const float* ln_in_g = (const float*)d_in[15];
  const float* ln_in_b = (const float*)d_in[16];
  const float* ln_s_g  = (const float*)d_in[17];
  const float* ln_s_b  = (const float*)d_in[18];
  const float* ln_ff_g = (const float*)d_in[19];
  const float* ln_ff_b = (const float*)d_in[20];
  float* out = (float*)d_out;

  char* w = (char*)d_ws;
  u16* xbuf = (u16*)w;      w += (size_t)GM * 256 * 2;        // 128 MB (persistent)
  float* gUp = (float*)w;                                     // 8 MB partial region
  float* gdp = (float*)(w + (size_t)GB * NPART * 2048 * 4);
  w += (size_t)GB * NPART * 2048 * 4 + (size_t)GB * NPART * 8 * 4 + 4096;
  u16* wkv = (u16*)w;       w += (size_t)512 * 256 * 2;       // Wk|Wv bf16
  u16* Wcat = (u16*)w;      w += (size_t)1024 * 512 * 2;
  u16* W1b = (u16*)w;       w += (size_t)512 * 256 * 2;
  u16* W2b = (u16*)w;       w += (size_t)256 * 512 * 2;
  float* WqkT = (float*)w;  w += (size_t)256 * 256 * 4;
  u16* WqkTb = (u16*)w;     w += (size_t)256 * 256 * 2;
  float* slots = (float*)w; w += (size_t)131072 * 4;
  float* gqk = (float*)w;   w += (size_t)131072 * 4;

  u16* WvB = wkv + 65536;

  init_slots_kernel<<<512, 256, 0, stream>>>(noise, slots_mu, slots_ls, slots);
  wprep_kernel<<<3584, 256, 0, stream>>>(Wk, Wv, W_ih, W_hh, W1, W2, wkv, Wcat, W1b, W2b);
  wqk_kernel<<<256, 256, 0, stream>>>(Wk, Wq, WqkT, WqkTb);
  ln_bf16_kernel<<<GM / 4, 256, 0, stream>>>(inputs, ln_in_g, ln_in_b, xbuf);

  qproj_kernel<<<64, 256, 0, stream>>>(slots, WqkT, ln_s_g, ln_s_b, gqk);
  for (int it = 0; it < 3; ++it) {
    attn_kernel<<<dim3(NPART, GB), 256, 0, stream>>>(xbuf, gqk, gUp, gdp);
    update_kernel<<<64, 256, 0, stream>>>(gUp, gdp, slots, WvB, Wcat, b_ih, b_hh,
                                          W1b, b1, W2b, b2, ln_ff_g, ln_ff_b,
                                          WqkTb, ln_s_g, ln_s_b, gqk, out, it == 2);
  }
}

// Round 14
// 488.023 us; speedup vs baseline: 1.3015x; 1.3015x over previous
//
#include <hip/hip_runtime.h>

typedef unsigned short u16;
typedef unsigned int u32;
typedef __attribute__((ext_vector_type(4))) float f32x4;
typedef __attribute__((ext_vector_type(8))) short s16x8;

#define GM 262144   // B*N rows
#define GB 64
#define GN 4096
#define GS 8
#define NPART 16    // PX-partial blocks per batch

#define GLDS16(G, L) __builtin_amdgcn_global_load_lds( \
    (const __attribute__((address_space(1))) void*)(G), \
    (__attribute__((address_space(3))) void*)(L), 16, 0, 0)

__device__ __forceinline__ float bf2f(u16 u) {
  union { unsigned int i; float f; } c; c.i = ((unsigned int)u) << 16; return c.f;
}
__device__ __forceinline__ u16 f2bf(float f) {
  union { float f; unsigned int i; } c; c.f = f;
  unsigned int x = c.i;
  unsigned int r = x + 0x7FFFu + ((x >> 16) & 1u);
  return (u16)(r >> 16);
}
__device__ __forceinline__ float dot4(f32x4 a, f32x4 b) {
  return a.x*b.x + a.y*b.y + a.z*b.z + a.w*b.w;
}

// ---------------- merged prologue: slots init | weight prep | WqkT ----------------
// blocks [0,512): init slots; [512,4096): wprep; [4096,4352): wqk.
__global__ __launch_bounds__(256) void prologue_kernel(
    const float* __restrict__ noise, const float* __restrict__ smu, const float* __restrict__ sls,
    float* __restrict__ slots,
    const float* __restrict__ Wk, const float* __restrict__ Wv,
    const float* __restrict__ Wih, const float* __restrict__ Whh,
    const float* __restrict__ W1, const float* __restrict__ W2,
    const float* __restrict__ Wq,
    u16* __restrict__ wkv, u16* __restrict__ Wcat,
    u16* __restrict__ W1b, u16* __restrict__ W2b,
    float* __restrict__ WqkT, u16* __restrict__ WqkTb)
{
  __shared__ float wkc[256];
  const int bid = blockIdx.x;
  const int t = threadIdx.x;
  if (bid < 512) {
    int i = bid * 256 + t;
    int d = i & 255;
    slots[i] = smu[d] + expf(sls[d]) * noise[i];
  } else if (bid < 4096) {
    int i = (bid - 512) * 256 + t;        // 917504 total
    if (i < 131072) {
      wkv[i] = f2bf(i < 65536 ? Wk[i] : Wv[i - 65536]);
    } else if (i < 655360) {
      int j2 = i - 131072;
      int r = j2 >> 9, k = j2 & 511;
      float v;
      if (r < 512)      v = (k < 256) ? Wih[r * 256 + k] : Whh[r * 256 + (k - 256)];
      else if (r < 768) v = (k < 256) ? Wih[r * 256 + k] : 0.f;
      else              v = (k < 256) ? 0.f : Whh[(r - 256) * 256 + (k - 256)];
      Wcat[j2] = f2bf(v);
    } else if (i < 786432) {
      W1b[i - 655360] = f2bf(W1[i - 655360]);
    } else {
      W2b[i - 786432] = f2bf(W2[i - 786432]);
    }
  } else {
    int c = bid - 4096;
    wkc[t] = Wk[t * 256 + c];
    __syncthreads();
    float a0 = 0.f, a1 = 0.f, a2 = 0.f, a3 = 0.f;
    #pragma unroll 4
    for (int d = 0; d < 256; d += 4) {
      a0 += wkc[d]     * Wq[(d)     * 256 + t];
      a1 += wkc[d + 1] * Wq[(d + 1) * 256 + t];
      a2 += wkc[d + 2] * Wq[(d + 2) * 256 + t];
      a3 += wkc[d + 3] * Wq[(d + 3) * 256 + t];
    }
    float acc = (a0 + a1 + a2 + a3) * 0.0625f;   // SCALE folded
    WqkT[c * 256 + t] = acc;
    WqkTb[c * 256 + t] = f2bf(acc);
  }
}

// ---------------- LN(inputs) -> bf16 xbuf (single layout) ----------------
__global__ __launch_bounds__(256) void ln_bf16_kernel(
    const float* __restrict__ x, const float* __restrict__ g, const float* __restrict__ be,
    u16* __restrict__ xbuf)
{
  int row = blockIdx.x * 4 + (threadIdx.x >> 6);
  int lane = threadIdx.x & 63;
  f32x4 v = *(const f32x4*)&x[(size_t)row * 256 + lane * 4];
  float s = v.x + v.y + v.z + v.w;
  float sq = v.x*v.x + v.y*v.y + v.z*v.z + v.w*v.w;
  #pragma unroll
  for (int m = 1; m < 64; m <<= 1) { s += __shfl_xor(s, m, 64); sq += __shfl_xor(sq, m, 64); }
  float mu = s * (1.f / 256.f);
  float var = sq * (1.f / 256.f) - mu * mu;
  float rstd = rsqrtf(var + 1e-3f);
  f32x4 gv = *(const f32x4*)&g[lane * 4];
  f32x4 bv = *(const f32x4*)&be[lane * 4];
  uint2 pk;
  pk.x = (u32)f2bf((v.x - mu) * rstd * gv.x + bv.x)
       | ((u32)f2bf((v.y - mu) * rstd * gv.y + bv.y) << 16);
  pk.y = (u32)f2bf((v.z - mu) * rstd * gv.z + bv.z)
       | ((u32)f2bf((v.w - mu) * rstd * gv.w + bv.w) << 16);
  *(uint2*)&xbuf[(size_t)row * 256 + lane * 4] = pk;
}

// ---------------- slot LN + q->input-space projection (iter 0 only) ----------------
__global__ __launch_bounds__(256) void qproj_kernel(const float* __restrict__ slots,
    const float* __restrict__ WqkT,
    const float* __restrict__ g, const float* __restrict__ be, float* __restrict__ gqk)
{
  __shared__ __align__(16) float sl[8][256];
  int b = blockIdx.x, t = threadIdx.x;
  int lane = t & 63, w = t >> 6;
  #pragma unroll
  for (int s2 = 0; s2 < 2; ++s2) {
    int s = w * 2 + s2;
    f32x4 v = *(const f32x4*)&slots[(size_t)(b * 8 + s) * 256 + lane * 4];
    float s1 = v.x + v.y + v.z + v.w;
    float q1 = v.x*v.x + v.y*v.y + v.z*v.z + v.w*v.w;
    #pragma unroll
    for (int m = 1; m < 64; m <<= 1) { s1 += __shfl_xor(s1, m, 64); q1 += __shfl_xor(q1, m, 64); }
    float mu = s1 * (1.f / 256.f);
    float var = q1 * (1.f / 256.f) - mu * mu;
    float rstd = rsqrtf(var + 1e-3f);
    f32x4 gv = *(const f32x4*)&g[lane * 4];
    f32x4 bv = *(const f32x4*)&be[lane * 4];
    f32x4 o;
    o.x = (v.x - mu) * rstd * gv.x + bv.x;
    o.y = (v.y - mu) * rstd * gv.y + bv.y;
    o.z = (v.z - mu) * rstd * gv.z + bv.z;
    o.w = (v.w - mu) * rstd * gv.w + bv.w;
    *(f32x4*)&sl[s][lane * 4] = o;
  }
  __syncthreads();
  float a[8];
  #pragma unroll
  for (int s = 0; s < 8; ++s) a[s] = 0.f;
  const f32x4* wr = (const f32x4*)&WqkT[(size_t)t * 256];
  for (int k = 0; k < 64; ++k) {
    f32x4 w4 = wr[k];
    #pragma unroll
    for (int s = 0; s < 8; ++s) a[s] += dot4(w4, *(const f32x4*)&sl[s][k * 4]);
  }
  #pragma unroll
  for (int s = 0; s < 8; ++s) gqk[(size_t)(b * 8 + s) * 256 + t] = a[s];
}

// ---------------- single-layout MFMA attention with in-LDS transpose (round-11) ----------------
// grid (16, 64), block 256 = 4 waves. Block loops over 4 tiles (64 n x 256 c each):
// stage tile once (GLDS16, chunk-XOR swizzle f(n)), dots from LDS rows, PV from LDS
// columns — swizzle is conflict-free for BOTH. Wave w owns U columns w*64..w*64+64.
__global__ __launch_bounds__(256) void attn_kernel(
    const u16* __restrict__ xb, const float* __restrict__ gqk,
    float* __restrict__ gUp, float* __restrict__ gdp)
{
  __shared__ __align__(16) u16 X[64 * 256];     // swizzled tile, 32 KB
  __shared__ __align__(16) u16 P[16 * 72];      // P[s][n] bf16 (rows 8..15 zero)
  __shared__ float denL[4][8];
  const int b = blockIdx.y, chunk = blockIdx.x;
  const int t = threadIdx.x;
  const int lane = t & 63, w = t >> 6;
  const int fr = lane & 15, fq = lane >> 4;
  const bool valid = fr < 8;

  // zero P rows 8..15 once (never written again)
  for (int i = t; i < 288; i += 256) ((u32*)P)[288 + i] = 0;

  // --- q fragments (B operand for dots): slot = fr ---
  s16x8 qf[8];
  if (valid) {
    const float* qr = gqk + (size_t)b * 2048 + fr * 256;
    #pragma unroll
    for (int ks = 0; ks < 8; ++ks) {
      f32x4 a = *(const f32x4*)&qr[ks * 32 + fq * 8];
      f32x4 c = *(const f32x4*)&qr[ks * 32 + fq * 8 + 4];
      s16x8 q8;
      q8[0] = (short)f2bf(a.x); q8[1] = (short)f2bf(a.y);
      q8[2] = (short)f2bf(a.z); q8[3] = (short)f2bf(a.w);
      q8[4] = (short)f2bf(c.x); q8[5] = (short)f2bf(c.y);
      q8[6] = (short)f2bf(c.z); q8[7] = (short)f2bf(c.w);
      qf[ks] = q8;
    }
  } else {
    #pragma unroll
    for (int ks = 0; ks < 8; ++ks) { s16x8 z = {0,0,0,0,0,0,0,0}; qf[ks] = z; }
  }

  // swizzle constants: f(n) = (n.bit3 << 2) | (n.bit4 << 1)
  const int fnA = ((fr >> 1) & 4) | ((w & 1) << 1);       // dots rows: n = w*16 + fr
  const int fnB = ((fq & 1) << 2) | ((fq >> 1) << 1);     // PV cols: n = ch*32 + fq*8 + j

  float denom_loc = 0.f;
  f32x4 uacc[4];
  #pragma unroll
  for (int ct = 0; ct < 4; ++ct) { f32x4 z = {0.f,0.f,0.f,0.f}; uacc[ct] = z; }

  for (int ti = 0; ti < 4; ++ti) {
    const u16* src = xb + ((size_t)b * 4096 + (size_t)(chunk * 4 + ti) * 64) * 256;
    __syncthreads();                             // prev tile (X cols + P) fully consumed
    // stage tile: 2048 16B-chunks; LDS linear, global source pre-swizzled
    #pragma unroll
    for (int p = 0; p < 8; ++p) {
      int q = p * 256 + t;
      int n = q >> 5, cl = q & 31;
      int fn = ((n >> 1) & 4) | ((n >> 3) & 2);
      GLDS16(src + (size_t)n * 256 + ((cl ^ fn) * 8), &X[q * 8]);
    }
    asm volatile("s_waitcnt vmcnt(0)");
    __syncthreads();

    // --- dots: wave w -> rows n = w*16 + fr ; D[n][s] ---
    f32x4 dacc = {0.f, 0.f, 0.f, 0.f};
    {
      const u16* xrow = &X[(w * 16 + fr) * 256];
      #pragma unroll
      for (int ks = 0; ks < 8; ++ks) {
        s16x8 a = *(const s16x8*)&xrow[(((ks * 4 + fq) ^ fnA) * 8)];
        dacc = __builtin_amdgcn_mfma_f32_16x16x32_bf16(a, qf[ks], dacc, 0, 0, 0);
      }
    }
    // --- softmax over slots (fr bits 0..2); rows n = w*16 + fq*4 + r ---
    float pw[4];
    #pragma unroll
    for (int r = 0; r < 4; ++r) {
      float d = dacc[r];
      float m = d;
      #pragma unroll
      for (int msk = 1; msk < 8; msk <<= 1) m = fmaxf(m, __shfl_xor(m, msk, 64));
      float e = expf(d - m);
      float sm = e;
      #pragma unroll
      for (int msk = 1; msk < 8; msk <<= 1) sm += __shfl_xor(sm, msk, 64);
      pw[r] = valid ? (e / sm + 1e-8f) : 0.f;
    }
    denom_loc += pw[0] + pw[1] + pw[2] + pw[3];
    if (valid) {
      u32* p32 = (u32*)P;
      int pi = fr * 36 + w * 8 + fq * 2;
      p32[pi]     = (u32)f2bf(pw[0]) | ((u32)f2bf(pw[1]) << 16);
      p32[pi + 1] = (u32)f2bf(pw[2]) | ((u32)f2bf(pw[3]) << 16);
    }
    __syncthreads();                             // P complete (all waves)

    // --- PV: U[s][c], wave w -> c in [w*64, w*64+64); X^T via LDS column reads ---
    #pragma unroll
    for (int ch = 0; ch < 2; ++ch) {
      s16x8 pa = *(const s16x8*)&P[fr * 72 + ch * 32 + fq * 8];
      #pragma unroll
      for (int ct = 0; ct < 4; ++ct) {
        int c = w * 64 + ct * 16 + fr;
        const u16* xcol = &X[(ch * 32 + fq * 8) * 256 + (((c >> 3) ^ fnB) * 8) + (c & 7)];
        union { s16x8 v; u32 u[4]; } vb;
        #pragma unroll
        for (int jj = 0; jj < 4; ++jj) {
          u16 e0 = xcol[(jj * 2) * 256];
          u16 e1 = xcol[(jj * 2 + 1) * 256];
          vb.u[jj] = (u32)e0 | ((u32)e1 << 16);
        }
        uacc[ct] = __builtin_amdgcn_mfma_f32_16x16x32_bf16(pa, vb.v, uacc[ct], 0, 0, 0);
      }
    }
  }

  // --- epilogue: wave-owned U columns -> f32 partial; denom block-reduce ---
  float dl = denom_loc;
  dl += __shfl_xor(dl, 16, 64);
  dl += __shfl_xor(dl, 32, 64);
  if (lane < 8) denL[w][lane] = dl;
  if (fq < 2) {
    size_t obase = (size_t)(b * NPART + chunk) * 2048;
    #pragma unroll
    for (int ct = 0; ct < 4; ++ct)
      #pragma unroll
      for (int r = 0; r < 4; ++r)
        gUp[obase + (size_t)(fq * 4 + r) * 256 + w * 64 + ct * 16 + fr] = uacc[ct][r];
  }
  __syncthreads();
  if (t < 8) gdp[(b * NPART + chunk) * 8 + t] = denL[0][t] + denL[1][t] + denL[2][t] + denL[3][t];
}

// ---------------- update: Wv-proj + GRU + LN + MLP (+ fused next-iter qproj) ----------------
__global__ __launch_bounds__(256) void update_kernel(
    const float* __restrict__ gUp, const float* __restrict__ gdp,
    float* __restrict__ slots,
    const u16* __restrict__ WvB,
    const u16* __restrict__ Wcat, const float* __restrict__ b_ih, const float* __restrict__ b_hh,
    const u16* __restrict__ W1b, const float* __restrict__ b1,
    const u16* __restrict__ W2b, const float* __restrict__ b2,
    const float* __restrict__ lng, const float* __restrict__ lnb,
    const u16* __restrict__ WqkTb, const float* __restrict__ lnsg, const float* __restrict__ lnsb,
    float* __restrict__ gqk, float* __restrict__ out, int last)
{
  __shared__ __align__(16) u16 bufA[16 * 520];
  __shared__ __align__(16) u16 bufP[16 * 264];
  __shared__ __align__(16) u16 bufU[16 * 264];
  __shared__ float g[1024 * 10];
  __shared__ float nl[8 * 256];
  __shared__ float sp[8 * 256];
  __shared__ float scr[16];
  const int b = blockIdx.x;
  const int t = threadIdx.x;
  const int lane = t & 63, w = t >> 6;
  const int fr = lane & 15, fq = lane >> 4;

  // ---- phase 0 ----
  #pragma unroll
  for (int s = 0; s < 8; ++s) {
    float den = 0.f, ua = 0.f;
    #pragma unroll 4
    for (int c = 0; c < NPART; ++c) {
      den += gdp[(b * NPART + c) * 8 + s];
      ua  += gUp[(size_t)(b * NPART + c) * 2048 + s * 256 + t];
    }
    bufU[s * 264 + t] = f2bf(ua / den);
    float spv = slots[(b * 8 + s) * 256 + t];
    bufA[s * 520 + 256 + t] = f2bf(spv);
    sp[s * 256 + t] = spv;
  }
  for (int i = t; i < 8 * 520; i += 256) bufA[8 * 520 + i] = 0;
  for (int i = t; i < 8 * 264; i += 256) { bufP[8 * 264 + i] = 0; bufU[8 * 264 + i] = 0; }
  __syncthreads();

  // ---- phase 0b: updates = PXn @ Wv^T -> bufA u-half ----
  {
    s16x8 pa[8];
    #pragma unroll
    for (int ks = 0; ks < 8; ++ks)
      pa[ks] = *(const s16x8*)&bufU[fr * 264 + ks * 32 + fq * 8];
    for (int nf = 0; nf < 4; ++nf) {
      int n0 = w * 64 + nf * 16;
      f32x4 acc = {0.f, 0.f, 0.f, 0.f};
      #pragma unroll
      for (int ks = 0; ks < 8; ++ks) {
        s16x8 bb = *(const s16x8*)&WvB[(size_t)(n0 + fr) * 256 + ks * 32 + fq * 8];
        acc = __builtin_amdgcn_mfma_f32_16x16x32_bf16(pa[ks], bb, acc, 0, 0, 0);
      }
      if (fq < 2) {
        int d = n0 + fr;
        #pragma unroll
        for (int r = 0; r < 4; ++r)
          bufA[(fq * 4 + r) * 520 + d] = f2bf(acc[r]);
      }
    }
  }
  __syncthreads();

  // ---- phase 1: gates GEMM M=16 N=1024 K=512 ----
  {
    s16x8 afr[16];
    #pragma unroll
    for (int ks = 0; ks < 16; ++ks)
      afr[ks] = *(const s16x8*)&bufA[fr * 520 + ks * 32 + fq * 8];
    for (int nf = 0; nf < 16; ++nf) {
      int n0 = w * 256 + nf * 16;
      f32x4 acc = {0.f, 0.f, 0.f, 0.f};
      #pragma unroll
      for (int ks = 0; ks < 16; ++ks) {
        s16x8 bb = *(const s16x8*)&Wcat[(size_t)(n0 + fr) * 512 + ks * 32 + fq * 8];
        acc = __builtin_amdgcn_mfma_f32_16x16x32_bf16(afr[ks], bb, acc, 0, 0, 0);
      }
      if (fq < 2) {
        int j = n0 + fr;
        #pragma unroll
        for (int r = 0; r < 4; ++r) g[j * 10 + fq * 4 + r] = acc[r];
      }
    }
  }
  __syncthreads();

  // ---- phase 2: GRU elementwise ----
  {
    float bi0 = b_ih[t],       bh0 = b_hh[t];
    float bi1 = b_ih[256 + t], bh1 = b_hh[256 + t];
    float bi2 = b_ih[512 + t], bh2 = b_hh[512 + t];
    #pragma unroll
    for (int s = 0; s < 8; ++s) {
      float rr = 1.f / (1.f + expf(-(g[t * 10 + s] + bi0 + bh0)));
      float z  = 1.f / (1.f + expf(-(g[(256 + t) * 10 + s] + bi1 + bh1)));
      float xn = g[(512 + t) * 10 + s] + bi2;
      float hn = g[(768 + t) * 10 + s] + bh2;
      float nn = tanhf(xn + rr * hn);
      nl[s * 256 + t] = (1.f - z) * nn + z * sp[s * 256 + t];
    }
  }
  __syncthreads();

  // ---- LN_ff ----
  {
    int ln_ = t & 63;
    #pragma unroll
    for (int j = 0; j < 2; ++j) {
      int sl = w * 2 + j;
      f32x4 v = *(const f32x4*)&nl[sl * 256 + ln_ * 4];
      float s1 = v.x + v.y + v.z + v.w;
      float s2 = v.x*v.x + v.y*v.y + v.z*v.z + v.w*v.w;
      #pragma unroll
      for (int m = 1; m < 64; m <<= 1) { s1 += __shfl_xor(s1, m, 64); s2 += __shfl_xor(s2, m, 64); }
      if (ln_ == 0) {
        float mu = s1 * (1.f / 256.f);
        float var = s2 * (1.f / 256.f) - mu * mu;
        scr[sl * 2] = mu;
        scr[sl * 2 + 1] = rsqrtf(var + 1e-3f);
      }
    }
  }
  __syncthreads();
  {
    float lg = lng[t], lb = lnb[t];
    #pragma unroll
    for (int s = 0; s < 8; ++s)
      bufP[s * 264 + t] = f2bf((nl[s * 256 + t] - scr[s * 2]) * scr[s * 2 + 1] * lg + lb);
  }
  __syncthreads();

  // ---- phase 3: MLP1 M=16 N=512 K=256, relu ----
  {
    s16x8 pa[8];
    #pragma unroll
    for (int ks = 0; ks < 8; ++ks)
      pa[ks] = *(const s16x8*)&bufP[fr * 264 + ks * 32 + fq * 8];
    for (int nf = 0; nf < 8; ++nf) {
      int n0 = w * 128 + nf * 16;
      f32x4 acc = {0.f, 0.f, 0.f, 0.f};
      #pragma unroll
      for (int ks = 0; ks < 8; ++ks) {
        s16x8 bb = *(const s16x8*)&W1b[(size_t)(n0 + fr) * 256 + ks * 32 + fq * 8];
        acc = __builtin_amdgcn_mfma_f32_16x16x32_bf16(pa[ks], bb, acc, 0, 0, 0);
      }
      if (fq < 2) {
        float bb1 = b1[n0 + fr];
        #pragma unroll
        for (int r = 0; r < 4; ++r)
          bufA[(fq * 4 + r) * 520 + n0 + fr] = f2bf(fmaxf(acc[r] + bb1, 0.f));
      }
    }
  }
  __syncthreads();

  // ---- phase 4: MLP2 M=16 N=256 K=512, +residual; new slots -> sp ----
  {
    s16x8 ha[16];
    #pragma unroll
    for (int ks = 0; ks < 16; ++ks)
      ha[ks] = *(const s16x8*)&bufA[fr * 520 + ks * 32 + fq * 8];
    for (int nf = 0; nf < 4; ++nf) {
      int n0 = w * 64 + nf * 16;
      f32x4 acc = {0.f, 0.f, 0.f, 0.f};
      #pragma unroll
      for (int ks = 0; ks < 16; ++ks) {
        s16x8 bb = *(const s16x8*)&W2b[(size_t)(n0 + fr) * 512 + ks * 32 + fq * 8];
        acc = __builtin_amdgcn_mfma_f32_16x16x32_bf16(ha[ks], bb, acc, 0, 0, 0);
      }
      if (fq < 2) {
        int d = n0 + fr;
        float bb2 = b2[d];
        #pragma unroll
        for (int r = 0; r < 4; ++r) {
          int sl = fq * 4 + r;
          float val = acc[r] + nl[sl * 256 + d] + bb2;
          slots[(b * 8 + sl) * 256 + d] = val;
          sp[sl * 256 + d] = val;
          if (last) out[(b * 8 + sl) * 256 + d] = val;
        }
      }
    }
  }
  if (last) return;
  __syncthreads();

  // ---- fused next-iter qproj: gqk = LN_s(new slots) @ WqkT (SCALE folded) ----
  {
    int ln_ = t & 63;
    #pragma unroll
    for (int j = 0; j < 2; ++j) {
      int sl = w * 2 + j;
      f32x4 v = *(const f32x4*)&sp[sl * 256 + ln_ * 4];
      float s1 = v.x + v.y + v.z + v.w;
      float s2 = v.x*v.x + v.y*v.y + v.z*v.z + v.w*v.w;
      #pragma unroll
      for (int m = 1; m < 64; m <<= 1) { s1 += __shfl_xor(s1, m, 64); s2 += __shfl_xor(s2, m, 64); }
      if (ln_ == 0) {
        float mu = s1 * (1.f / 256.f);
        float var = s2 * (1.f / 256.f) - mu * mu;
        scr[sl * 2] = mu;
        scr[sl * 2 + 1] = rsqrtf(var + 1e-3f);
      }
    }
  }
  __syncthreads();
  {
    float lg = lnsg[t], lb = lnsb[t];
    #pragma unroll
    for (int s = 0; s < 8; ++s)
      bufP[s * 264 + t] = f2bf((sp[s * 256 + t] - scr[s * 2]) * scr[s * 2 + 1] * lg + lb);
  }
  __syncthreads();
  {
    s16x8 pa[8];
    #pragma unroll
    for (int ks = 0; ks < 8; ++ks)
      pa[ks] = *(const s16x8*)&bufP[fr * 264 + ks * 32 + fq * 8];
    for (int nf = 0; nf < 4; ++nf) {
      int n0 = w * 64 + nf * 16;
      f32x4 acc = {0.f, 0.f, 0.f, 0.f};
      #pragma unroll
      for (int ks = 0; ks < 8; ++ks) {
        s16x8 bb = *(const s16x8*)&WqkTb[(size_t)(n0 + fr) * 256 + ks * 32 + fq * 8];
        acc = __builtin_amdgcn_mfma_f32_16x16x32_bf16(pa[ks], bb, acc, 0, 0, 0);
      }
      if (fq < 2) {
        int e = n0 + fr;
        #pragma unroll
        for (int r = 0; r < 4; ++r)
          gqk[(size_t)(b * 8 + fq * 4 + r) * 256 + e] = acc[r];
      }
    }
  }
}

extern "C" void kernel_launch(void* const* d_in, const int* in_sizes, int n_in,
                              void* d_out, int out_size, void* d_ws, size_t ws_size,
                              hipStream_t stream) {
  const float* inputs   = (const float*)d_in[0];
  const float* noise    = (const float*)d_in[1];
  const float* slots_mu = (const float*)d_in[2];
  const float* slots_ls = (const float*)d_in[3];
  const float* Wq   = (const float*)d_in[4];
  const float* Wk   = (const float*)d_in[5];
  const float* Wv   = (const float*)d_in[6];
  const float* W_ih = (const float*)d_in[7];
  const float* W_hh = (const float*)d_in[8];
  const float* b_ih = (const float*)d_in[9];
  const float* b_hh = (const float*)d_in[10];
  const float* W1   = (const float*)d_in[11];
  const float* b1   = (const float*)d_in[12];
  const float* W2   = (const float*)d_in[13];
  const float* b2   = (const float*)d_in[14];
  const float* ln_in_g = (const float*)d_in[15];
  const float* ln_in_b = (const float*)d_in[16];
  const float* ln_s_g  = (const float*)d_in[17];
  const float* ln_s_b  = (const float*)d_in[18];
  const float* ln_ff_g = (const float*)d_in[19];
  const float* ln_ff_b = (const float*)d_in[20];
  float* out = (float*)d_out;

  char* w = (char*)d_ws;
  u16* xbuf = (u16*)w;      w += (size_t)GM * 256 * 2;        // 128 MB (persistent)
  float* gUp = (float*)w;                                     // 8 MB partial region
  float* gdp = (float*)(w + (size_t)GB * NPART * 2048 * 4);
  w += (size_t)GB * NPART * 2048 * 4 + (size_t)GB * NPART * 8 * 4 + 4096;
  u16* wkv = (u16*)w;       w += (size_t)512 * 256 * 2;       // Wk|Wv bf16
  u16* Wcat = (u16*)w;      w += (size_t)1024 * 512 * 2;
  u16* W1b = (u16*)w;       w += (size_t)512 * 256 * 2;
  u16* W2b = (u16*)w;       w += (size_t)256 * 512 * 2;
  float* WqkT = (float*)w;  w += (size_t)256 * 256 * 4;
  u16* WqkTb = (u16*)w;     w += (size_t)256 * 256 * 2;
  float* slots = (float*)w; w += (size_t)131072 * 4;
  float* gqk = (float*)w;   w += (size_t)131072 * 4;

  u16* WvB = wkv + 65536;

  prologue_kernel<<<4352, 256, 0, stream>>>(noise, slots_mu, slots_ls, slots,
                                            Wk, Wv, W_ih, W_hh, W1, W2, Wq,
                                            wkv, Wcat, W1b, W2b, WqkT, WqkTb);
  ln_bf16_kernel<<<GM / 4, 256, 0, stream>>>(inputs, ln_in_g, ln_in_b, xbuf);

  qproj_kernel<<<64, 256, 0, stream>>>(slots, WqkT, ln_s_g, ln_s_b, gqk);
  for (int it = 0; it < 3; ++it) {
    attn_kernel<<<dim3(NPART, GB), 256, 0, stream>>>(xbuf, gqk, gUp, gdp);
    update_kernel<<<64, 256, 0, stream>>>(gUp, gdp, slots, WvB, Wcat, b_ih, b_hh,
                                          W1b, b1, W2b, b2, ln_ff_g, ln_ff_b,
                                          WqkTb, ln_s_g, ln_s_b, gqk, out, it == 2);
  }
}